// Round 1
// baseline (2663.174 us; speedup 1.0000x reference)
//
#include <hip/hip_runtime.h>
#include <math.h>

// Problem dims
#define BB 32
#define NN 32
#define EE 256
#define HH 1500
#define G4 6000      // 4*HH
#define QIN 512
#define Q1O 600
#define QO 300
#define EV1 1000
#define EV2 100
#define EV3 10
#define PP 496       // N*(N-1)/2
#define ROWS (BB*PP) // 15872
#define KS 16        // lstm k-split
#define KCH 94       // ceil(1500/16)

__device__ __forceinline__ float sigm(float x) { return 1.f / (1.f + expf(-x)); }

// ---------------- init helpers ----------------
__global__ void k_zero(float* a, int n) {
    int i = blockIdx.x * 256 + threadIdx.x;
    if (i < n) a[i] = 0.f;
}

__global__ void k_iijj(int* iijj) {
    int p = threadIdx.x;
    if (p >= PP) return;
    int i = 0, p0 = 0;
    while (p >= p0 + (NN - 1 - i)) { p0 += NN - 1 - i; i++; }
    iijj[p] = i;
    iijj[PP + p] = i + 1 + (p - p0);
}

// q1 effective bias: q1_b[o] + sum over odd k of q1_w[o][k]  (PE at pos 0)
__global__ void k_q1beff(const float* q1w, const float* q1b, float* beff) {
    int o = blockIdx.x * 256 + threadIdx.x;
    if (o >= Q1O) return;
    float a = q1b[o];
    for (int k = 1; k < QIN; k += 2) a += q1w[o * QIN + k];
    beff[o] = a;
}

// ---------------- transpose (sub-range of columns) ----------------
// src[R][C], take columns [c0, c0+csub) -> dst[csub][R]
__global__ void k_transpose(const float* __restrict__ src, float* __restrict__ dst,
                            int R, int C, int c0, int csub) {
    __shared__ float tile[32][33];
    int cb = blockIdx.x * 32, rb = blockIdx.y * 32;
    for (int dy = threadIdx.y; dy < 32; dy += 8) {
        int r = rb + dy, c = cb + threadIdx.x;
        if (r < R && c < csub) tile[dy][threadIdx.x] = src[(size_t)r * C + c0 + c];
    }
    __syncthreads();
    for (int dy = threadIdx.y; dy < 32; dy += 8) {
        int c = cb + dy, r = rb + threadIdx.x;
        if (c < csub && r < R) dst[(size_t)c * R + r] = tile[threadIdx.x][dy];
    }
}

// ---------------- sort along parts axis ----------------
// x[b][n][e] -> seq[n][b][e] with values sorted over n per (b,e)
__global__ void k_sort(const float* __restrict__ x, float* __restrict__ seq) {
    int tid = blockIdx.x * 256 + threadIdx.x;
    if (tid >= BB * EE) return;
    int b = tid / EE, e = tid % EE;
    float v[NN];
    for (int n = 0; n < NN; n++) v[n] = x[(b * NN + n) * EE + e];
    for (int i = 1; i < NN; i++) {
        float key = v[i];
        int j = i - 1;
        while (j >= 0 && v[j] > key) { v[j + 1] = v[j]; j--; }
        v[j + 1] = key;
    }
    for (int n = 0; n < NN; n++) seq[(n * BB + b) * EE + e] = v[n];
}

// ---------------- x-side gates for all steps ----------------
// xg[r][j] = seq_row[r] . w_ih[j] + b_ih[j] + b_hh[j], r = n*32+b (1024 rows), j<6000
__global__ void k_xg(const float* __restrict__ seq, const float* __restrict__ wih_t,
                     const float* __restrict__ b_ih, const float* __restrict__ b_hh,
                     float* __restrict__ xg) {
    __shared__ float in_s[16 * EE];
    int r0 = blockIdx.y * 16;
    for (int idx = threadIdx.x; idx < 16 * EE; idx += 256)
        in_s[idx] = seq[(size_t)r0 * EE + idx];
    __syncthreads();
    int j = blockIdx.x * 256 + threadIdx.x;
    if (j >= G4) return;
    float acc[16];
#pragma unroll
    for (int r = 0; r < 16; r++) acc[r] = 0.f;
    for (int k = 0; k < EE; k++) {
        float w = wih_t[(size_t)k * G4 + j];
#pragma unroll
        for (int r = 0; r < 16; r++) acc[r] += in_s[r * EE + k] * w;
    }
    float bv = b_ih[j] + b_hh[j];
#pragma unroll
    for (int r = 0; r < 16; r++) xg[(size_t)(r0 + r) * G4 + j] = acc[r] + bv;
}

// ---------------- LSTM recurrent GEMM (split-K partials) ----------------
// grid (6 jh-chunks, 4 b-groups of 8, 16 k-chunks), block 256
__global__ void k_lstm_gemm(const float* __restrict__ h, const float* __restrict__ whh_t,
                            float* __restrict__ gpart) {
    __shared__ float hs[8][KCH + 2];
    int jh = blockIdx.x * 256 + threadIdx.x;
    int b0 = blockIdx.y * 8;
    int k0 = blockIdx.z * KCH;
    int klen = min(KCH, HH - k0);
    for (int idx = threadIdx.x; idx < 8 * klen; idx += 256) {
        int bb = idx / klen, kk = idx % klen;
        hs[bb][kk] = h[(b0 + bb) * HH + k0 + kk];
    }
    __syncthreads();
    if (jh < HH) {
        float acc[8][4];
#pragma unroll
        for (int bb = 0; bb < 8; bb++)
#pragma unroll
            for (int g = 0; g < 4; g++) acc[bb][g] = 0.f;
        for (int kk = 0; kk < klen; kk++) {
            const float* wrow = whh_t + (size_t)(k0 + kk) * G4;
            float wi = wrow[jh], wf = wrow[HH + jh], wg = wrow[2 * HH + jh], wo = wrow[3 * HH + jh];
#pragma unroll
            for (int bb = 0; bb < 8; bb++) {
                float hv = hs[bb][kk];
                acc[bb][0] += hv * wi;
                acc[bb][1] += hv * wf;
                acc[bb][2] += hv * wg;
                acc[bb][3] += hv * wo;
            }
        }
#pragma unroll
        for (int bb = 0; bb < 8; bb++)
#pragma unroll
            for (int g = 0; g < 4; g++)
                gpart[(size_t)(blockIdx.z * BB + b0 + bb) * G4 + g * HH + jh] = acc[bb][g];
    }
}

// ---------------- LSTM gate nonlinearity + state update ----------------
__global__ void k_lstm_gate(const float* __restrict__ xg_n, const float* __restrict__ gpart,
                            float* __restrict__ c, float* __restrict__ h_out) {
    int idx = blockIdx.x * 256 + threadIdx.x;
    if (idx >= BB * HH) return;
    int b = idx / HH, jh = idx % HH;
    float g4[4];
#pragma unroll
    for (int g = 0; g < 4; g++) {
        float v = xg_n[(size_t)b * G4 + g * HH + jh];
        for (int s = 0; s < KS; s++) v += gpart[(size_t)(s * BB + b) * G4 + g * HH + jh];
        g4[g] = v;
    }
    float ci = c[idx];
    float cn = sigm(g4[1]) * ci + sigm(g4[0]) * tanhf(g4[2]);
    c[idx] = cn;
    h_out[idx] = sigm(g4[3]) * tanhf(cn);
}

// ---------------- plan-side e1 bias: pb[b][o] = e1_b[o] + plan[b] . e1_w[o][:1500] ----------------
__global__ void k_pb(const float* __restrict__ plan, const float* __restrict__ e1at,
                     const float* __restrict__ e1b, float* __restrict__ pb) {
    __shared__ float ps[HH];
    int b = blockIdx.y;
    for (int idx = threadIdx.x; idx < HH; idx += 256) ps[idx] = plan[b * HH + idx];
    __syncthreads();
    int o = blockIdx.x * 256 + threadIdx.x;
    if (o >= EV1) return;
    float acc = e1b[o];
    for (int k = 0; k < HH; k++) acc += ps[k] * e1at[(size_t)k * EV1 + o];
    pb[b * EV1 + o] = acc;
}

// ---------------- q1: gather pair input + GEMM + relu ----------------
// grid (3 o-chunks, 992 row-groups of 16)
__global__ void k_q1(const float* __restrict__ x, const int* __restrict__ iijj,
                     const float* __restrict__ q1t, const float* __restrict__ beff,
                     float* __restrict__ out) {
    __shared__ float in_s[16 * QIN];
    int r0 = blockIdx.y * 16;
    for (int idx = threadIdx.x; idx < 16 * QIN; idx += 256) {
        int rr = idx >> 9, k = idx & 511;
        int r = r0 + rr, b = r / PP, p = r % PP;
        int part = (k < EE) ? iijj[p] : iijj[PP + p];
        in_s[idx] = x[(size_t)(b * NN + part) * EE + (k & (EE - 1))];
    }
    __syncthreads();
    int o = blockIdx.x * 256 + threadIdx.x;
    if (o >= Q1O) return;
    float acc[16];
#pragma unroll
    for (int r = 0; r < 16; r++) acc[r] = 0.f;
    for (int k = 0; k < QIN; k++) {
        float w = q1t[(size_t)k * Q1O + o];
#pragma unroll
        for (int r = 0; r < 16; r++) acc[r] += in_s[r * QIN + k] * w;
    }
    float bv = beff[o];
#pragma unroll
    for (int r = 0; r < 16; r++) out[(size_t)(r0 + r) * Q1O + o] = fmaxf(acc[r] + bv, 0.f);
}

// ---------------- generic row-blocked MLP layer: out = relu(in @ wt + bias [+ pb]) ----------------
// grid (ceil(O/256), ROWS/16), dynamic LDS = 16*K floats
__global__ void k_mlp(const float* __restrict__ in, const float* __restrict__ wt,
                      const float* __restrict__ bias, const float* __restrict__ pbm,
                      float* __restrict__ out, int K, int O) {
    extern __shared__ float in_s[];
    int r0 = blockIdx.y * 16;
    for (int idx = threadIdx.x; idx < 16 * K; idx += 256)
        in_s[idx] = in[(size_t)r0 * K + idx];
    __syncthreads();
    int o = blockIdx.x * 256 + threadIdx.x;
    if (o >= O) return;
    float acc[16];
#pragma unroll
    for (int r = 0; r < 16; r++) acc[r] = 0.f;
    for (int k = 0; k < K; k++) {
        float w = wt[(size_t)k * O + o];
#pragma unroll
        for (int r = 0; r < 16; r++) acc[r] += in_s[r * K + k] * w;
    }
#pragma unroll
    for (int r = 0; r < 16; r++) {
        float bv = (bias ? bias[o] : 0.f) + (pbm ? pbm[((r0 + r) / PP) * O + o] : 0.f);
        out[(size_t)(r0 + r) * O + o] = fmaxf(acc[r] + bv, 0.f);
    }
}

// ---------------- fused e3 + e4 tail ----------------
__global__ void k_e34(const float* __restrict__ e2out, const float* __restrict__ e3t,
                      const float* __restrict__ e3b, const float* __restrict__ e4w,
                      const float* __restrict__ e4b, float* __restrict__ out) {
    __shared__ float wt[EV2 * EV3];
    for (int idx = threadIdx.x; idx < EV2 * EV3; idx += 256) wt[idx] = e3t[idx];
    __syncthreads();
    int r = blockIdx.x * 256 + threadIdx.x;
    if (r >= ROWS) return;
    float h3[EV3];
#pragma unroll
    for (int o3 = 0; o3 < EV3; o3++) h3[o3] = e3b[o3];
    for (int k = 0; k < EV2; k++) {
        float v = e2out[(size_t)r * EV2 + k];
#pragma unroll
        for (int o3 = 0; o3 < EV3; o3++) h3[o3] += v * wt[k * EV3 + o3];
    }
    float acc = e4b[0];
#pragma unroll
    for (int o3 = 0; o3 < EV3; o3++) acc += fmaxf(h3[o3], 0.f) * e4w[o3];
    out[r] = fmaxf(acc, 0.f);
}

// ---------------- host launch ----------------
extern "C" void kernel_launch(void* const* d_in, const int* in_sizes, int n_in,
                              void* d_out, int out_size, void* d_ws, size_t ws_size,
                              hipStream_t stream) {
    const float* x    = (const float*)d_in[0];
    const float* w_ih = (const float*)d_in[1];
    const float* w_hh = (const float*)d_in[2];
    const float* b_ih = (const float*)d_in[3];
    const float* b_hh = (const float*)d_in[4];
    const float* q1_w = (const float*)d_in[5];
    const float* q1_b = (const float*)d_in[6];
    const float* q2_w = (const float*)d_in[7];
    const float* q2_b = (const float*)d_in[8];
    const float* e1_w = (const float*)d_in[9];
    const float* e1_b = (const float*)d_in[10];
    const float* e2_w = (const float*)d_in[11];
    const float* e2_b = (const float*)d_in[12];
    const float* e3_w = (const float*)d_in[13];
    const float* e3_b = (const float*)d_in[14];
    const float* e4_w = (const float*)d_in[15];
    const float* e4_b = (const float*)d_in[16];
    float* out = (float*)d_out;
    float* ws = (float*)d_ws;

    // workspace layout (float offsets)
    size_t off = 0;
    float* seq    = ws + off; off += (size_t)NN * BB * EE;          // 262144
    size_t regionA = off;
    float* wih_t  = ws + off; off += (size_t)EE * G4;               // 1,536,000
    float* whh_t  = ws + off; off += (size_t)HH * G4;               // 9,000,000
    float* xg     = ws + off; off += (size_t)NN * BB * G4;          // 6,144,000
    float* e1out  = ws + regionA;                                   // alias (15,872,000 fits)
    float* h0     = ws + off; off += BB * HH;
    float* h1     = ws + off; off += BB * HH;
    float* cst    = ws + off; off += BB * HH;
    float* gpart  = ws + off; off += (size_t)KS * BB * G4;          // 3,072,000
    float* q1t    = ws + off; off += (size_t)QIN * Q1O;
    float* q1beff = ws + off; off += 1024;
    float* q2t    = ws + off; off += (size_t)Q1O * QO;
    float* e1at   = ws + off; off += (size_t)HH * EV1;
    float* e1bt   = ws + off; off += (size_t)QO * EV1;
    float* e2t    = ws + off; off += (size_t)EV1 * EV2;
    float* e3t    = ws + off; off += 1024;
    float* pb     = ws + off; off += BB * EV1;
    float* q1out  = ws + off; off += (size_t)ROWS * Q1O;
    float* q2out  = ws + off; off += (size_t)ROWS * QO;
    float* e2out  = ws + off; off += (size_t)ROWS * EV2;
    int*   iijj   = (int*)(ws + off); off += 1024;

    dim3 tb(32, 8);

    // init
    k_iijj<<<1, 512, 0, stream>>>(iijj);
    k_q1beff<<<3, 256, 0, stream>>>(q1_w, q1_b, q1beff);
    k_zero<<<188, 256, 0, stream>>>(h0, BB * HH);
    k_zero<<<188, 256, 0, stream>>>(cst, BB * HH);

    // weight transposes to [K][O]
    k_transpose<<<dim3(8, 188), tb, 0, stream>>>(w_ih, wih_t, G4, EE, 0, EE);
    k_transpose<<<dim3(47, 188), tb, 0, stream>>>(w_hh, whh_t, G4, HH, 0, HH);
    k_transpose<<<dim3(16, 19), tb, 0, stream>>>(q1_w, q1t, Q1O, QIN, 0, QIN);
    k_transpose<<<dim3(19, 10), tb, 0, stream>>>(q2_w, q2t, QO, Q1O, 0, Q1O);
    k_transpose<<<dim3(47, 32), tb, 0, stream>>>(e1_w, e1at, EV1, HH + QO, 0, HH);
    k_transpose<<<dim3(10, 32), tb, 0, stream>>>(e1_w, e1bt, EV1, HH + QO, HH, QO);
    k_transpose<<<dim3(32, 4), tb, 0, stream>>>(e2_w, e2t, EV2, EV1, 0, EV1);
    k_transpose<<<dim3(4, 1), tb, 0, stream>>>(e3_w, e3t, EV3, EV2, 0, EV2);

    // sort + x-side gates
    k_sort<<<32, 256, 0, stream>>>(x, seq);
    k_xg<<<dim3(24, 64), 256, 0, stream>>>(seq, wih_t, b_ih, b_hh, xg);

    // LSTM: 32 sequential steps
    float* hbuf[2] = {h0, h1};
    for (int n = 0; n < NN; n++) {
        k_lstm_gemm<<<dim3(6, 4, KS), 256, 0, stream>>>(hbuf[n & 1], whh_t, gpart);
        k_lstm_gate<<<188, 256, 0, stream>>>(xg + (size_t)n * BB * G4, gpart, cst, hbuf[(n + 1) & 1]);
    }
    float* plan = hbuf[0]; // after 32 steps

    // evaluator plan-side bias
    k_pb<<<dim3(4, BB), 256, 0, stream>>>(plan, e1at, e1_b, pb);

    // pair MLP
    k_q1<<<dim3(3, ROWS / 16), 256, 0, stream>>>(x, iijj, q1t, q1beff, q1out);
    k_mlp<<<dim3(2, ROWS / 16), 256, 16 * Q1O * 4, stream>>>(q1out, q2t, q2_b, nullptr, q2out, Q1O, QO);
    k_mlp<<<dim3(4, ROWS / 16), 256, 16 * QO * 4, stream>>>(q2out, e1bt, nullptr, pb, e1out, QO, EV1);
    k_mlp<<<dim3(1, ROWS / 16), 256, 16 * EV1 * 4, stream>>>(e1out, e2t, e2_b, nullptr, e2out, EV1, EV2);
    k_e34<<<62, 256, 0, stream>>>(e2out, e3t, e3_b, e4_w, e4_b, out);
}